// Round 1
// baseline (2000.458 us; speedup 1.0000x reference)
//
#include <hip/hip_runtime.h>

#define N_NODES 50000
#define N_EDGES 600000
#define N_GRAPHS 2048
#define EMB 128
#define HN (N_NODES * EMB)  // 6,400,000 floats per [N, EMB] buffer

// ---------------- Atom encoder: h[n,e] = sum_c atom_emb[c, x[n,c], e] ----------------
__global__ __launch_bounds__(128) void k_atom(const int* __restrict__ x,
                                              const float* __restrict__ atom_emb,
                                              float* __restrict__ h) {
  int n = blockIdx.x, e = threadIdx.x;
  const int* xr = x + n * 9;
  float acc = 0.f;
#pragma unroll
  for (int c = 0; c < 9; ++c) {
    acc += atom_emb[(c * 100 + xr[c]) * EMB + e];
  }
  h[n * EMB + e] = acc;
}

// ---------------- xw[k][n][e] = sum_j h[n][j] * Wl[k][j][e], k=0..2 ----------------
// 32 nodes per block, 256 threads: e = tid&127, row-group rg = tid>>7, 16 rows/thread.
__global__ __launch_bounds__(256) void k_gemm3(const float* __restrict__ h,
                                               const float* __restrict__ Wl,  // [3][128][128]
                                               float* __restrict__ xw) {      // [3][N][128]
  __shared__ float hs[32 * EMB];
  const int nb = blockIdx.x * 32;
  const int tid = threadIdx.x;
  for (int i = tid; i < 32 * EMB; i += 256) {
    int r = i >> 7;
    hs[i] = (nb + r < N_NODES) ? h[(nb + r) * EMB + (i & 127)] : 0.f;
  }
  __syncthreads();
  const int e = tid & 127, rg = tid >> 7;
  float acc0[16], acc1[16], acc2[16];
#pragma unroll
  for (int r = 0; r < 16; ++r) acc0[r] = acc1[r] = acc2[r] = 0.f;
  const float* w0 = Wl + e;
  const float* w1 = Wl + 128 * 128 + e;
  const float* w2 = Wl + 2 * 128 * 128 + e;
  for (int j = 0; j < EMB; ++j) {
    float wa = w0[j * 128], wb = w1[j * 128], wc = w2[j * 128];
#pragma unroll
    for (int r = 0; r < 16; ++r) {
      float hv = hs[(rg + 2 * r) * EMB + j];
      acc0[r] += hv * wa;
      acc1[r] += hv * wb;
      acc2[r] += hv * wc;
    }
  }
#pragma unroll
  for (int r = 0; r < 16; ++r) {
    int n = nb + rg + 2 * r;
    if (n < N_NODES) {
      xw[n * EMB + e]          = acc0[r];
      xw[HN + n * EMB + e]     = acc1[r];
      xw[2 * HN + n * EMB + e] = acc2[r];
    }
  }
}

// ---------------- Edge scatter: agg[dst] += sum_k ew[k] * xw_k[src] ----------------
// One wave per edge (4 edges / 256-thread block); each lane handles 2 columns (float2).
__global__ __launch_bounds__(256) void k_edge(const int* __restrict__ ei,
                                              const int* __restrict__ ea,
                                              const float* __restrict__ bl,  // bond_emb[layer]: [3][8][3]
                                              const float* __restrict__ xw,
                                              float* __restrict__ agg) {
  const int edge = blockIdx.x * 4 + (threadIdx.x >> 6);
  const int lane = threadIdx.x & 63;
  const int src = ei[edge];
  const int dst = ei[N_EDGES + edge];
  const int a0 = ea[edge * 3 + 0], a1 = ea[edge * 3 + 1], a2 = ea[edge * 3 + 2];
  const float ew0 = bl[a0 * 3 + 0] + bl[24 + a1 * 3 + 0] + bl[48 + a2 * 3 + 0];
  const float ew1 = bl[a0 * 3 + 1] + bl[24 + a1 * 3 + 1] + bl[48 + a2 * 3 + 1];
  const float ew2 = bl[a0 * 3 + 2] + bl[24 + a1 * 3 + 2] + bl[48 + a2 * 3 + 2];
  const float2* p0 = (const float2*)(xw + (size_t)src * EMB);
  const float2* p1 = (const float2*)(xw + HN + (size_t)src * EMB);
  const float2* p2 = (const float2*)(xw + 2 * HN + (size_t)src * EMB);
  float2 v0 = p0[lane], v1 = p1[lane], v2 = p2[lane];
  float m0 = ew0 * v0.x + ew1 * v1.x + ew2 * v2.x;
  float m1 = ew0 * v0.y + ew1 * v1.y + ew2 * v2.y;
  float* aout = agg + (size_t)dst * EMB + lane * 2;
  atomicAdd(aout, m0);
  atomicAdd(aout + 1, m1);
}

// ---------------- hn = agg + bias_sum; relu?; h = hn + h ----------------
__global__ __launch_bounds__(256) void k_post(float* __restrict__ h,
                                              const float* __restrict__ agg,
                                              const float* __restrict__ bl,  // b[layer]: [3][128]
                                              int do_relu) {
  int idx = blockIdx.x * 256 + threadIdx.x;
  if (idx >= HN) return;
  int e = idx & 127;
  float bias = bl[e] + bl[128 + e] + bl[256 + e];
  float hn = agg[idx] + bias;
  if (do_relu) hn = fmaxf(hn, 0.f);
  h[idx] = hn + h[idx];
}

// ---------------- mean-pool scatter ----------------
__global__ __launch_bounds__(128) void k_pool(const float* __restrict__ h,
                                              const int* __restrict__ batch,
                                              float* __restrict__ sums,
                                              float* __restrict__ counts) {
  int n = blockIdx.x, e = threadIdx.x;
  int g = batch[n];
  atomicAdd(&sums[g * EMB + e], h[n * EMB + e]);
  if (e == 0) atomicAdd(&counts[g], 1.f);
}

// ---------------- head: out[g] = (hg@fc1 + b1) @ fc2 + b2 ----------------
__global__ __launch_bounds__(128) void k_head(const float* __restrict__ sums,
                                              const float* __restrict__ counts,
                                              const float* __restrict__ fc1_w,
                                              const float* __restrict__ fc1_b,
                                              const float* __restrict__ fc2_w,
                                              const float* __restrict__ fc2_b,
                                              float* __restrict__ out) {
  __shared__ float hg[EMB];
  __shared__ float red[EMB];
  int g = blockIdx.x, e = threadIdx.x;
  float cnt = fmaxf(counts[g], 1.f);
  hg[e] = sums[g * EMB + e] / cnt;
  __syncthreads();
  float acc = fc1_b[e];
  for (int j = 0; j < EMB; ++j) acc += hg[j] * fc1_w[j * EMB + e];
  red[e] = acc * fc2_w[e];
  __syncthreads();
  for (int s = 64; s > 0; s >>= 1) {
    if (e < s) red[e] += red[e + s];
    __syncthreads();
  }
  if (e == 0) out[g] = red[0] + fc2_b[0];
}

extern "C" void kernel_launch(void* const* d_in, const int* in_sizes, int n_in,
                              void* d_out, int out_size, void* d_ws, size_t ws_size,
                              hipStream_t stream) {
  const int*   x        = (const int*)d_in[0];
  const int*   ei       = (const int*)d_in[1];   // [2, E]: src row, then dst row
  const int*   ea       = (const int*)d_in[2];   // [E, 3]
  const int*   batch    = (const int*)d_in[3];
  const float* atom_emb = (const float*)d_in[4]; // [9,100,128]
  const float* bond_emb = (const float*)d_in[5]; // [3,3,8,3]
  const float* W        = (const float*)d_in[6]; // [3,3,128,128]
  const float* b        = (const float*)d_in[7]; // [3,3,128]
  const float* fc1_w    = (const float*)d_in[8];
  const float* fc1_b    = (const float*)d_in[9];
  const float* fc2_w    = (const float*)d_in[10];
  const float* fc2_b    = (const float*)d_in[11];
  float* out = (float*)d_out;

  float* ws     = (float*)d_ws;
  float* h      = ws;            // HN floats
  float* xw     = ws + HN;       // 3*HN floats
  float* agg    = ws + 4 * HN;   // HN floats
  float* sums   = ws + 5 * HN;   // N_GRAPHS*EMB
  float* counts = sums + N_GRAPHS * EMB;  // N_GRAPHS

  k_atom<<<N_NODES, 128, 0, stream>>>(x, atom_emb, h);

  for (int layer = 0; layer < 3; ++layer) {
    k_gemm3<<<(N_NODES + 31) / 32, 256, 0, stream>>>(h, W + layer * 3 * EMB * EMB, xw);
    hipMemsetAsync(agg, 0, (size_t)HN * sizeof(float), stream);
    k_edge<<<N_EDGES / 4, 256, 0, stream>>>(ei, ea, bond_emb + layer * 72, xw, agg);
    k_post<<<HN / 256, 256, 0, stream>>>(h, agg, b + layer * 3 * EMB, layer < 2 ? 1 : 0);
  }

  hipMemsetAsync(sums, 0, (size_t)(N_GRAPHS * EMB + N_GRAPHS) * sizeof(float), stream);
  k_pool<<<N_NODES, 128, 0, stream>>>(h, batch, sums, counts);
  k_head<<<N_GRAPHS, 128, 0, stream>>>(sums, counts, fc1_w, fc1_b, fc2_w, fc2_b, out);
}

// Round 2
// 871.304 us; speedup vs baseline: 2.2959x; 2.2959x over previous
//
#include <hip/hip_runtime.h>

#define N_NODES 50000
#define N_EDGES 600000
#define N_GRAPHS 2048
#define EMB 128
#define TDIM 384                 // 3 * EMB, stacked message dim
#define HN (N_NODES * EMB)       // floats in one [N, EMB] buffer

// ---------------- Atom encoder: h[n,e] = sum_c atom_emb[c, x[n,c], e] ----------------
__global__ __launch_bounds__(128) void k_atom(const int* __restrict__ x,
                                              const float* __restrict__ atom_emb,
                                              float* __restrict__ h) {
  int n = blockIdx.x, e = threadIdx.x;
  const int* xr = x + n * 9;
  float acc = 0.f;
#pragma unroll
  for (int c = 0; c < 9; ++c) acc += atom_emb[(c * 100 + xr[c]) * EMB + e];
  h[n * EMB + e] = acc;
}

// ---------------- CSR build ----------------
__global__ __launch_bounds__(256) void k_hist(const int* __restrict__ ei, int* __restrict__ deg) {
  int e = blockIdx.x * 256 + threadIdx.x;
  if (e < N_EDGES) atomicAdd(&deg[ei[N_EDGES + e]], 1);
}

// single block, 256 threads: exclusive prefix sum of deg[50000] -> row_start, cursor
__global__ __launch_bounds__(256) void k_scan(const int* __restrict__ deg,
                                              int* __restrict__ row_start,
                                              int* __restrict__ cursor) {
  __shared__ int part[256];
  const int tid = threadIdx.x;
  const int chunk = (N_NODES + 255) / 256;  // 196
  const int base = tid * chunk;
  int s = 0;
  for (int i = 0; i < chunk; ++i) {
    int idx = base + i;
    if (idx < N_NODES) s += deg[idx];
  }
  part[tid] = s;
  __syncthreads();
  for (int off = 1; off < 256; off <<= 1) {
    int v = (tid >= off) ? part[tid - off] : 0;
    __syncthreads();
    part[tid] += v;
    __syncthreads();
  }
  int run = (tid == 0) ? 0 : part[tid - 1];
  for (int i = 0; i < chunk; ++i) {
    int idx = base + i;
    if (idx < N_NODES) {
      row_start[idx] = run;
      cursor[idx] = run;
      run += deg[idx];
    }
  }
  if (tid == 255) row_start[N_NODES] = part[255];
}

__global__ __launch_bounds__(256) void k_scatter(const int* __restrict__ ei,
                                                 const int* __restrict__ ea,
                                                 int* __restrict__ cursor,
                                                 int* __restrict__ sorted_src,
                                                 int* __restrict__ sorted_eap) {
  int e = blockIdx.x * 256 + threadIdx.x;
  if (e >= N_EDGES) return;
  int src = ei[e], dst = ei[N_EDGES + e];
  int pos = atomicAdd(&cursor[dst], 1);
  sorted_src[pos] = src;
  sorted_eap[pos] = ea[e * 3 + 0] | (ea[e * 3 + 1] << 3) | (ea[e * 3 + 2] << 6);
}

// ---------------- Edge aggregation: t[n][k*128+c] = sum_{e into n} ew[e,k] * h[src(e)][c] ----------------
// One wave per node (4 nodes per 256-thread block); lane handles cols 2*lane, 2*lane+1.
__global__ __launch_bounds__(256) void k_agg(const int* __restrict__ sorted_src,
                                             const int* __restrict__ sorted_eap,
                                             const int* __restrict__ row_start,
                                             const float* __restrict__ bl,  // bond_emb[layer]: [3][8][3]
                                             const float* __restrict__ h,
                                             float* __restrict__ t) {
  __shared__ float combo[512 * 3];  // ew for every (a0,a1,a2) combo
  for (int c = threadIdx.x; c < 512; c += 256) {
    int a0 = c & 7, a1 = (c >> 3) & 7, a2 = (c >> 6) & 7;
#pragma unroll
    for (int k = 0; k < 3; ++k)
      combo[c * 3 + k] = bl[a0 * 3 + k] + bl[24 + a1 * 3 + k] + bl[48 + a2 * 3 + k];
  }
  __syncthreads();
  const int node = blockIdx.x * 4 + (threadIdx.x >> 6);
  const int lane = threadIdx.x & 63;
  const int beg = row_start[node], end = row_start[node + 1];
  float2 acc0 = {0.f, 0.f}, acc1 = {0.f, 0.f}, acc2 = {0.f, 0.f};
  for (int e = beg; e < end; ++e) {
    int src = sorted_src[e];
    int pk = sorted_eap[e];
    float2 hv = *(const float2*)(h + (size_t)src * EMB + lane * 2);
    float w0 = combo[pk * 3 + 0], w1 = combo[pk * 3 + 1], w2 = combo[pk * 3 + 2];
    acc0.x += w0 * hv.x; acc0.y += w0 * hv.y;
    acc1.x += w1 * hv.x; acc1.y += w1 * hv.y;
    acc2.x += w2 * hv.x; acc2.y += w2 * hv.y;
  }
  float* tr = t + (size_t)node * TDIM + lane * 2;
  *(float2*)(tr)       = acc0;
  *(float2*)(tr + 128) = acc1;
  *(float2*)(tr + 256) = acc2;
}

// ---------------- Fused GEMM + bias + relu + residual ----------------
// agg[n][c] = sum_j t[n][j] * Wl[j][c]; h[n][c] = relu?(agg+biassum) + h[n][c]
// Block: 32 nodes x 128 cols. 256 threads: tx=tid&31 (cols tx*4..+3), ty=tid>>5 (rows ty*4..+3).
__global__ __launch_bounds__(256) void k_gemm_fused(const float* __restrict__ t,
                                                    const float* __restrict__ Wl,  // [384][128]
                                                    const float* __restrict__ bl,  // [3][128]
                                                    float* __restrict__ h,
                                                    int do_relu) {
  __shared__ float ts[32 * TDIM];  // 48 KB
  const int nb = blockIdx.x * 32;
  // stage t rows (guard last partial block)
  const float4* tg = (const float4*)(t + (size_t)nb * TDIM);
  float4* tsv = (float4*)ts;
  for (int i = threadIdx.x; i < 32 * TDIM / 4; i += 256) {
    int row = i / (TDIM / 4);
    tsv[i] = (nb + row < N_NODES) ? tg[i] : float4{0.f, 0.f, 0.f, 0.f};
  }
  __syncthreads();
  const int tx = threadIdx.x & 31;   // col group: cols tx*4..tx*4+3
  const int ty = threadIdx.x >> 5;   // rows ty*4..ty*4+3
  float4 acc[4];
#pragma unroll
  for (int r = 0; r < 4; ++r) acc[r] = float4{0.f, 0.f, 0.f, 0.f};
  const float* wc = Wl + tx * 4;
  for (int j = 0; j < TDIM; j += 4) {
    float4 w0 = *(const float4*)(wc + (j + 0) * EMB);
    float4 w1 = *(const float4*)(wc + (j + 1) * EMB);
    float4 w2 = *(const float4*)(wc + (j + 2) * EMB);
    float4 w3 = *(const float4*)(wc + (j + 3) * EMB);
#pragma unroll
    for (int r = 0; r < 4; ++r) {
      float4 hv = *(const float4*)(ts + (ty * 4 + r) * TDIM + j);
      acc[r].x += hv.x * w0.x + hv.y * w1.x + hv.z * w2.x + hv.w * w3.x;
      acc[r].y += hv.x * w0.y + hv.y * w1.y + hv.z * w2.y + hv.w * w3.y;
      acc[r].z += hv.x * w0.z + hv.y * w1.z + hv.z * w2.z + hv.w * w3.z;
      acc[r].w += hv.x * w0.w + hv.y * w1.w + hv.z * w2.w + hv.w * w3.w;
    }
  }
  // epilogue: bias sum, relu, residual
  float4 b0 = *(const float4*)(bl + tx * 4);
  float4 b1 = *(const float4*)(bl + 128 + tx * 4);
  float4 b2 = *(const float4*)(bl + 256 + tx * 4);
  float4 bias = {b0.x + b1.x + b2.x, b0.y + b1.y + b2.y,
                 b0.z + b1.z + b2.z, b0.w + b1.w + b2.w};
#pragma unroll
  for (int r = 0; r < 4; ++r) {
    int n = nb + ty * 4 + r;
    if (n < N_NODES) {
      float4* hp = (float4*)(h + (size_t)n * EMB + tx * 4);
      float4 hv = *hp;
      float4 v = {acc[r].x + bias.x, acc[r].y + bias.y,
                  acc[r].z + bias.z, acc[r].w + bias.w};
      if (do_relu) {
        v.x = fmaxf(v.x, 0.f); v.y = fmaxf(v.y, 0.f);
        v.z = fmaxf(v.z, 0.f); v.w = fmaxf(v.w, 0.f);
      }
      hv.x += v.x; hv.y += v.y; hv.z += v.z; hv.w += v.w;
      *hp = hv;
    }
  }
}

// ---------------- mean-pool scatter ----------------
__global__ __launch_bounds__(128) void k_pool(const float* __restrict__ h,
                                              const int* __restrict__ batch,
                                              float* __restrict__ sums,
                                              float* __restrict__ counts) {
  int n = blockIdx.x, e = threadIdx.x;
  int g = batch[n];
  atomicAdd(&sums[g * EMB + e], h[n * EMB + e]);
  if (e == 0) atomicAdd(&counts[g], 1.f);
}

// ---------------- head ----------------
__global__ __launch_bounds__(128) void k_head(const float* __restrict__ sums,
                                              const float* __restrict__ counts,
                                              const float* __restrict__ fc1_w,
                                              const float* __restrict__ fc1_b,
                                              const float* __restrict__ fc2_w,
                                              const float* __restrict__ fc2_b,
                                              float* __restrict__ out) {
  __shared__ float hg[EMB];
  __shared__ float red[EMB];
  int g = blockIdx.x, e = threadIdx.x;
  float cnt = fmaxf(counts[g], 1.f);
  hg[e] = sums[g * EMB + e] / cnt;
  __syncthreads();
  float acc = fc1_b[e];
  for (int j = 0; j < EMB; ++j) acc += hg[j] * fc1_w[j * EMB + e];
  red[e] = acc * fc2_w[e];
  __syncthreads();
  for (int s = 64; s > 0; s >>= 1) {
    if (e < s) red[e] += red[e + s];
    __syncthreads();
  }
  if (e == 0) out[g] = red[0] + fc2_b[0];
}

extern "C" void kernel_launch(void* const* d_in, const int* in_sizes, int n_in,
                              void* d_out, int out_size, void* d_ws, size_t ws_size,
                              hipStream_t stream) {
  const int*   x        = (const int*)d_in[0];
  const int*   ei       = (const int*)d_in[1];
  const int*   ea       = (const int*)d_in[2];
  const int*   batch    = (const int*)d_in[3];
  const float* atom_emb = (const float*)d_in[4];
  const float* bond_emb = (const float*)d_in[5];
  const float* W        = (const float*)d_in[6];
  const float* b        = (const float*)d_in[7];
  const float* fc1_w    = (const float*)d_in[8];
  const float* fc1_b    = (const float*)d_in[9];
  const float* fc2_w    = (const float*)d_in[10];
  const float* fc2_b    = (const float*)d_in[11];
  float* out = (float*)d_out;

  float* ws = (float*)d_ws;
  float* h          = ws;                       // HN floats            (25.6 MB)
  float* t          = h + HN;                   // N*384 floats         (76.8 MB)
  float* sums       = t + (size_t)N_NODES * TDIM;  // 2048*128
  float* counts     = sums + N_GRAPHS * EMB;    // 2048
  int*   deg        = (int*)(counts + N_GRAPHS);   // 50000
  int*   row_start  = deg + N_NODES;            // 50001
  int*   cursor     = row_start + N_NODES + 1;  // 50000
  int*   sorted_src = cursor + N_NODES;         // 600000
  int*   sorted_eap = sorted_src + N_EDGES;     // 600000

  hipMemsetAsync(deg, 0, N_NODES * sizeof(int), stream);
  k_atom<<<N_NODES, 128, 0, stream>>>(x, atom_emb, h);
  k_hist<<<(N_EDGES + 255) / 256, 256, 0, stream>>>(ei, deg);
  k_scan<<<1, 256, 0, stream>>>(deg, row_start, cursor);
  k_scatter<<<(N_EDGES + 255) / 256, 256, 0, stream>>>(ei, ea, cursor, sorted_src, sorted_eap);

  for (int layer = 0; layer < 3; ++layer) {
    k_agg<<<N_NODES / 4, 256, 0, stream>>>(sorted_src, sorted_eap, row_start,
                                           bond_emb + layer * 72, h, t);
    k_gemm_fused<<<(N_NODES + 31) / 32, 256, 0, stream>>>(
        t, W + (size_t)layer * 3 * EMB * EMB, b + layer * 3 * EMB, h, layer < 2 ? 1 : 0);
  }

  hipMemsetAsync(sums, 0, (N_GRAPHS * EMB + N_GRAPHS) * sizeof(float), stream);
  k_pool<<<N_NODES, 128, 0, stream>>>(h, batch, sums, counts);
  k_head<<<N_GRAPHS, 128, 0, stream>>>(sums, counts, fc1_w, fc1_b, fc2_w, fc2_b, out);
}